// Round 7
// baseline (1704.812 us; speedup 1.0000x reference)
//
#include <hip/hip_runtime.h>
#include <hip/hip_bf16.h>
#include <math.h>

typedef __bf16 bf16_8 __attribute__((ext_vector_type(8)));
typedef float f32x4 __attribute__((ext_vector_type(4)));

// ---------------------------------------------------------------- LayerNorm (fp32 in -> bf16 out)
__global__ __launch_bounds__(256) void ln_kernel(
    const float* __restrict__ x, const float* __restrict__ g,
    const float* __restrict__ b, __hip_bfloat16* __restrict__ out, int cols) {
  const int row = blockIdx.x;
  const int t = threadIdx.x;
  float loc[3];
  float s = 0.f, s2 = 0.f;
#pragma unroll
  for (int i = 0; i < 3; ++i) {
    float v = x[(size_t)row * cols + t + i * 256];
    loc[i] = v;
    s += v;
    s2 += v * v;
  }
#pragma unroll
  for (int off = 32; off; off >>= 1) {
    s += __shfl_down(s, off);
    s2 += __shfl_down(s2, off);
  }
  __shared__ float red[2][4];
  const int lane = t & 63, w = t >> 6;
  if (lane == 0) {
    red[0][w] = s;
    red[1][w] = s2;
  }
  __syncthreads();
  s = red[0][0] + red[0][1] + red[0][2] + red[0][3];
  s2 = red[1][0] + red[1][1] + red[1][2] + red[1][3];
  const float mu = s / cols;
  const float var = s2 / cols - mu * mu;
  const float rs = rsqrtf(var + 1e-5f);
  __hip_bfloat16* orow = out + (size_t)row * cols;
#pragma unroll
  for (int i = 0; i < 3; ++i) {
    int c = t + i * 256;
    orow[c] = __hip_bfloat16((loc[i] - mu) * rs * g[c] + b[c]);
  }
}

// ---------------------------------------------------------------- GEMM (A[M,K] bf16 ws @ B[N,K]^T fp32 input)
// MODE 0: out(bf16) = acc
// MODE 1: out(f32)  = resid_f32(x) + acc + bias
// MODE 2: out(bf16) = gelu_erf(acc + bias)
// MODE 3: out(f32)  = out_f32(same idx, = res) + acc + bias
template <int MODE>
__global__ __launch_bounds__(256) void gemm_bt(
    const __hip_bfloat16* __restrict__ A, const float* __restrict__ Bw,
    const float* __restrict__ bias, const float* __restrict__ resid,
    void* __restrict__ out, int M, int N, int K) {
  constexpr int BM = 128, BN = 128, BK = 32, LDP = 40;
  __shared__ __align__(16) __bf16 As[BM * LDP];
  __shared__ __align__(16) __bf16 Bs[BN * LDP];
  const int tid = threadIdx.x;
  const int m0 = blockIdx.y * BM;
  const int n0 = blockIdx.x * BN;
  const int wave = tid >> 6;
  const int lane = tid & 63;
  const int quad = lane >> 4;
  const int l16 = lane & 15;
  const int wm = (wave & 1) * 64;
  const int wn = (wave >> 1) * 64;

  f32x4 acc[4][4] = {};

  for (int k0 = 0; k0 < K; k0 += BK) {
    __syncthreads();
#pragma unroll
    for (int u = 0; u < 2; ++u) {
      int i = tid + u * 256;          // 0..511
      int row = i >> 2, kq = i & 3;   // row 0..127, 8-elem chunk 0..3
      *(bf16_8*)(&As[row * LDP + kq * 8]) =
          *(const bf16_8*)(A + (size_t)(m0 + row) * K + k0 + kq * 8);
      const float* src = Bw + (size_t)(n0 + row) * K + k0 + kq * 8;
      float4 f0 = *(const float4*)src;
      float4 f1 = *(const float4*)(src + 4);
      bf16_8 bv;
      bv[0] = (__bf16)f0.x; bv[1] = (__bf16)f0.y; bv[2] = (__bf16)f0.z; bv[3] = (__bf16)f0.w;
      bv[4] = (__bf16)f1.x; bv[5] = (__bf16)f1.y; bv[6] = (__bf16)f1.z; bv[7] = (__bf16)f1.w;
      *(bf16_8*)(&Bs[row * LDP + kq * 8]) = bv;
    }
    __syncthreads();
    bf16_8 af[4], bfr[4];
#pragma unroll
    for (int i = 0; i < 4; ++i)
      af[i] = *(const bf16_8*)(&As[(wm + i * 16 + l16) * LDP + quad * 8]);
#pragma unroll
    for (int j = 0; j < 4; ++j)
      bfr[j] = *(const bf16_8*)(&Bs[(wn + j * 16 + l16) * LDP + quad * 8]);
#pragma unroll
    for (int i = 0; i < 4; ++i)
#pragma unroll
      for (int j = 0; j < 4; ++j)
        acc[i][j] =
            __builtin_amdgcn_mfma_f32_16x16x32_bf16(af[i], bfr[j], acc[i][j], 0, 0, 0);
  }

#pragma unroll
  for (int i = 0; i < 4; ++i) {
#pragma unroll
    for (int j = 0; j < 4; ++j) {
#pragma unroll
      for (int r = 0; r < 4; ++r) {
        const int row = m0 + wm + i * 16 + quad * 4 + r;
        const int col = n0 + wn + j * 16 + l16;
        const size_t idx = (size_t)row * N + col;
        const float v = acc[i][j][r];
        if constexpr (MODE == 0) {
          ((__hip_bfloat16*)out)[idx] = __hip_bfloat16(v);
        } else if constexpr (MODE == 1) {
          ((float*)out)[idx] = resid[idx] + v + bias[col];
        } else if constexpr (MODE == 2) {
          float tt = v + bias[col];
          float gl = 0.5f * tt * (1.0f + erff(tt * 0.70710678118654752f));
          ((__hip_bfloat16*)out)[idx] = __hip_bfloat16(gl);
        } else {
          float rv = ((float*)out)[idx];  // res, written by MODE 1; same thread+idx
          ((float*)out)[idx] = rv + v + bias[col];
        }
      }
    }
  }
}

// ---------------------------------------------------------------- Causal attention
// One thread per query row, online softmax, K/V tiles staged in LDS (bf16 ws).
__global__ __launch_bounds__(256) void attn_kernel(
    const __hip_bfloat16* __restrict__ qb, const __hip_bfloat16* __restrict__ kb,
    const __hip_bfloat16* __restrict__ vb, __hip_bfloat16* __restrict__ ob) {
  const int S = 2048, H = 12, E = 768;
  const int bh = blockIdx.x;  // 0..23
  const int b = bh / H, h = bh % H;
  const int qt = blockIdx.y;  // 0..7
  const int t = threadIdx.x;
  const int s = qt * 256 + t;
  const size_t base = (size_t)b * S * E + (size_t)h * 64;

  float q[64], o[64];
  const __hip_bfloat16* qr = qb + base + (size_t)s * E;
#pragma unroll
  for (int d = 0; d < 64; ++d) q[d] = (float)qr[d];
#pragma unroll
  for (int d = 0; d < 64; ++d) o[d] = 0.f;
  float m = -1e30f, l = 0.f;

  __shared__ __align__(16) __bf16 Ks[64][64];
  __shared__ __align__(16) __bf16 Vs[64][64];
  const int ntiles = qt * 4 + 4;
  for (int kt = 0; kt < ntiles; ++kt) {
    __syncthreads();
#pragma unroll
    for (int u = 0; u < 2; ++u) {
      int i = t + u * 256;           // 0..511
      int kr = i >> 3, dq = i & 7;   // key row 0..63, 8-elem chunk 0..7
      int gk = kt * 64 + kr;
      *(bf16_8*)(&Ks[kr][dq * 8]) =
          *(const bf16_8*)(kb + base + (size_t)gk * E + dq * 8);
      *(bf16_8*)(&Vs[kr][dq * 8]) =
          *(const bf16_8*)(vb + base + (size_t)gk * E + dq * 8);
    }
    __syncthreads();
    for (int kk = 0; kk < 64; ++kk) {
      const int gk = kt * 64 + kk;
      if (gk <= s) {
        float dot = 0.f;
#pragma unroll
        for (int d = 0; d < 64; ++d) dot += q[d] * (float)Ks[kk][d];
        const float sc = dot * 0.125f;  // 1/sqrt(64)
        const float mn = fmaxf(m, sc);
        const float corr = __expf(m - mn);
        const float p = __expf(sc - mn);
        l = l * corr + p;
#pragma unroll
        for (int d = 0; d < 64; ++d) o[d] = o[d] * corr + p * (float)Vs[kk][d];
        m = mn;
      }
    }
  }
  const float inv = 1.f / l;
  __hip_bfloat16* orow = ob + base + (size_t)s * E;
#pragma unroll
  for (int d = 0; d < 64; ++d) orow[d] = __hip_bfloat16(o[d] * inv);
}

// ---------------------------------------------------------------- launch
extern "C" void kernel_launch(void* const* d_in, const int* in_sizes, int n_in,
                              void* d_out, int out_size, void* d_ws, size_t ws_size,
                              hipStream_t stream) {
  const int Bv = 2, S = 2048, E = 768, FF = 3072;
  const int M = Bv * S;  // 4096

  // Input assignment: dict order (x first) vs alphabetized pytree order (b1 first).
  int ix, iwq, iwk, iwv, iwo, ibo, iw1, ib1, iw2, ib2, ig, ibt;
  if (in_sizes[0] == M * E / (Bv * 2) * Bv * 2 || in_sizes[0] == 3145728) {
    // dict order: x wq wk wv wo bo w1 b1 w2 b2 gamma beta
    ix = 0; iwq = 1; iwk = 2; iwv = 3; iwo = 4; ibo = 5;
    iw1 = 6; ib1 = 7; iw2 = 8; ib2 = 9; ig = 10; ibt = 11;
  } else {
    // alphabetical: b1 b2 beta bo gamma w1 w2 wk wo wq wv x
    ib1 = 0; ib2 = 1; ibt = 2; ibo = 3; ig = 4; iw1 = 5; iw2 = 6;
    iwk = 7; iwo = 8; iwq = 9; iwv = 10; ix = 11;
  }
  const float* x = (const float*)d_in[ix];
  const float* wq = (const float*)d_in[iwq];
  const float* wk = (const float*)d_in[iwk];
  const float* wv = (const float*)d_in[iwv];
  const float* wo = (const float*)d_in[iwo];
  const float* bo = (const float*)d_in[ibo];
  const float* w1 = (const float*)d_in[iw1];
  const float* b1 = (const float*)d_in[ib1];
  const float* w2 = (const float*)d_in[iw2];
  const float* b2 = (const float*)d_in[ib2];
  const float* gamma = (const float*)d_in[ig];
  const float* beta = (const float*)d_in[ibt];

  // ws: 5 slots of M*E bf16 = 31.5 MB.
  //   s0: xn -> attn -> y    s1..s3: q,k,v    hbuf = s1..s4 (M*FF bf16)
  //   res (fp32) lives in d_out and is finalized in place.
  __hip_bfloat16* slot = (__hip_bfloat16*)d_ws;
  const size_t ME = (size_t)M * E;
  __hip_bfloat16* xn = slot;           // s0
  __hip_bfloat16* attn = slot;         // s0 reuse (xn dead)
  __hip_bfloat16* y = slot;            // s0 reuse (attn dead)
  __hip_bfloat16* q = slot + ME;       // s1
  __hip_bfloat16* k = slot + 2 * ME;   // s2
  __hip_bfloat16* v = slot + 3 * ME;   // s3
  __hip_bfloat16* hbuf = slot + ME;    // s1..s4 (q,k,v dead by then)
  float* res = (float*)d_out;          // fp32 residual, finalized in place

  // 1. LN1 (x fp32 -> xn bf16)
  ln_kernel<<<M, 256, 0, stream>>>(x, gamma, beta, xn, E);
  // 2. Q/K/V projections
  dim3 gE(E / 128, M / 128);
  gemm_bt<0><<<gE, 256, 0, stream>>>(xn, wq, nullptr, nullptr, q, M, E, E);
  gemm_bt<0><<<gE, 256, 0, stream>>>(xn, wk, nullptr, nullptr, k, M, E, E);
  gemm_bt<0><<<gE, 256, 0, stream>>>(xn, wv, nullptr, nullptr, v, M, E, E);
  // 3. causal attention (q,k,v -> attn in s0)
  attn_kernel<<<dim3(24, 8), 256, 0, stream>>>(q, k, v, attn);
  // 4. output projection + bias + residual(x fp32) -> res (fp32, in d_out)
  gemm_bt<1><<<gE, 256, 0, stream>>>(attn, wo, bo, x, res, M, E, E);
  // 5. LN2 (res fp32 -> y bf16 in s0)
  ln_kernel<<<M, 256, 0, stream>>>(res, gamma, beta, y, E);
  // 6. FFN up + GELU(erf) -> hbuf bf16 (s1..s4)
  dim3 gF(FF / 128, M / 128);
  gemm_bt<2><<<gF, 256, 0, stream>>>(y, w1, b1, nullptr, hbuf, M, FF, E);
  // 7. FFN down + bias, accumulated into res in place -> d_out (fp32)
  gemm_bt<3><<<gE, 256, 0, stream>>>(hbuf, w2, b2, nullptr, d_out, M, E, FF);
}

// Round 8
// 479.260 us; speedup vs baseline: 3.5572x; 3.5572x over previous
//
#include <hip/hip_runtime.h>
#include <hip/hip_bf16.h>
#include <math.h>

typedef __bf16 bf16_8 __attribute__((ext_vector_type(8)));
typedef float f32x4 __attribute__((ext_vector_type(4)));

// ---------------------------------------------------------------- LayerNorm (fp32 in -> bf16 out)
__global__ __launch_bounds__(256) void ln_kernel(
    const float* __restrict__ x, const float* __restrict__ g,
    const float* __restrict__ b, __hip_bfloat16* __restrict__ out, int cols) {
  const int row = blockIdx.x;
  const int t = threadIdx.x;
  float loc[3];
  float s = 0.f, s2 = 0.f;
#pragma unroll
  for (int i = 0; i < 3; ++i) {
    float v = x[(size_t)row * cols + t + i * 256];
    loc[i] = v;
    s += v;
    s2 += v * v;
  }
#pragma unroll
  for (int off = 32; off; off >>= 1) {
    s += __shfl_down(s, off);
    s2 += __shfl_down(s2, off);
  }
  __shared__ float red[2][4];
  const int lane = t & 63, w = t >> 6;
  if (lane == 0) {
    red[0][w] = s;
    red[1][w] = s2;
  }
  __syncthreads();
  s = red[0][0] + red[0][1] + red[0][2] + red[0][3];
  s2 = red[1][0] + red[1][1] + red[1][2] + red[1][3];
  const float mu = s / cols;
  const float var = s2 / cols - mu * mu;
  const float rs = rsqrtf(var + 1e-5f);
  __hip_bfloat16* orow = out + (size_t)row * cols;
#pragma unroll
  for (int i = 0; i < 3; ++i) {
    int c = t + i * 256;
    orow[c] = __hip_bfloat16((loc[i] - mu) * rs * g[c] + b[c]);
  }
}

// ---------------------------------------------------------------- GEMM (A[M,K] bf16 ws @ B[N,K]^T fp32 input)
// MODE 0: out(bf16) = acc
// MODE 1: out(f32)  = resid_f32(x) + acc + bias
// MODE 2: out(bf16) = gelu_erf(acc + bias)
// MODE 3: out(f32)  = out_f32(same idx, = res) + acc + bias
template <int MODE>
__global__ __launch_bounds__(256) void gemm_bt(
    const __hip_bfloat16* __restrict__ A, const float* __restrict__ Bw,
    const float* __restrict__ bias, const float* __restrict__ resid,
    void* __restrict__ out, int M, int N, int K) {
  constexpr int BM = 128, BN = 128, BK = 32, LDP = 40;
  __shared__ __align__(16) __bf16 As[BM * LDP];
  __shared__ __align__(16) __bf16 Bs[BN * LDP];
  const int tid = threadIdx.x;
  const int m0 = blockIdx.y * BM;
  const int n0 = blockIdx.x * BN;
  const int wave = tid >> 6;
  const int lane = tid & 63;
  const int quad = lane >> 4;
  const int l16 = lane & 15;
  const int wm = (wave & 1) * 64;
  const int wn = (wave >> 1) * 64;

  f32x4 acc[4][4] = {};

  for (int k0 = 0; k0 < K; k0 += BK) {
    __syncthreads();
#pragma unroll
    for (int u = 0; u < 2; ++u) {
      int i = tid + u * 256;          // 0..511
      int row = i >> 2, kq = i & 3;   // row 0..127, 8-elem chunk 0..3
      *(bf16_8*)(&As[row * LDP + kq * 8]) =
          *(const bf16_8*)(A + (size_t)(m0 + row) * K + k0 + kq * 8);
      const float* src = Bw + (size_t)(n0 + row) * K + k0 + kq * 8;
      float4 f0 = *(const float4*)src;
      float4 f1 = *(const float4*)(src + 4);
      bf16_8 bv;
      bv[0] = (__bf16)f0.x; bv[1] = (__bf16)f0.y; bv[2] = (__bf16)f0.z; bv[3] = (__bf16)f0.w;
      bv[4] = (__bf16)f1.x; bv[5] = (__bf16)f1.y; bv[6] = (__bf16)f1.z; bv[7] = (__bf16)f1.w;
      *(bf16_8*)(&Bs[row * LDP + kq * 8]) = bv;
    }
    __syncthreads();
    bf16_8 af[4], bfr[4];
#pragma unroll
    for (int i = 0; i < 4; ++i)
      af[i] = *(const bf16_8*)(&As[(wm + i * 16 + l16) * LDP + quad * 8]);
#pragma unroll
    for (int j = 0; j < 4; ++j)
      bfr[j] = *(const bf16_8*)(&Bs[(wn + j * 16 + l16) * LDP + quad * 8]);
#pragma unroll
    for (int i = 0; i < 4; ++i)
#pragma unroll
      for (int j = 0; j < 4; ++j)
        acc[i][j] =
            __builtin_amdgcn_mfma_f32_16x16x32_bf16(af[i], bfr[j], acc[i][j], 0, 0, 0);
  }

#pragma unroll
  for (int i = 0; i < 4; ++i) {
#pragma unroll
    for (int j = 0; j < 4; ++j) {
#pragma unroll
      for (int r = 0; r < 4; ++r) {
        const int row = m0 + wm + i * 16 + quad * 4 + r;
        const int col = n0 + wn + j * 16 + l16;
        const size_t idx = (size_t)row * N + col;
        const float v = acc[i][j][r];
        if constexpr (MODE == 0) {
          ((__hip_bfloat16*)out)[idx] = __hip_bfloat16(v);
        } else if constexpr (MODE == 1) {
          ((float*)out)[idx] = resid[idx] + v + bias[col];
        } else if constexpr (MODE == 2) {
          float tt = v + bias[col];
          float gl = 0.5f * tt * (1.0f + erff(tt * 0.70710678118654752f));
          ((__hip_bfloat16*)out)[idx] = __hip_bfloat16(gl);
        } else {
          float rv = ((float*)out)[idx];  // res, written by MODE 1; same thread+idx
          ((float*)out)[idx] = rv + v + bias[col];
        }
      }
    }
  }
}

// ---------------------------------------------------------------- MFMA flash attention
// Grid: (24 bh, 32 q-tiles). Block: 256 thr = 4 waves; wave owns 16 queries.
// Per 64-key tile: QK^T (8 mfma) -> online softmax (C-layout regs) ->
// P via wave-private LDS (C->A layout) -> PV (8 mfma, V staged transposed).
#define ALDP 72  // LDS leading dim: 144B rows -> 16B-aligned b128, bank stride 4
__global__ __launch_bounds__(256) void attn_mfma(
    const __hip_bfloat16* __restrict__ qb, const __hip_bfloat16* __restrict__ kb,
    const __hip_bfloat16* __restrict__ vb, __hip_bfloat16* __restrict__ ob) {
  const int S = 2048, H = 12, E = 768;
  const int bh = blockIdx.x;          // 0..23
  const int b = bh / H, h = bh % H;
  const int qblk = 31 - blockIdx.y;   // heaviest q-tiles dispatch first
  const int q0 = qblk * 64;
  const int tid = threadIdx.x;
  const int wave = tid >> 6;
  const int lane = tid & 63;
  const int quad = lane >> 4;
  const int l16 = lane & 15;
  const size_t base = (size_t)b * S * E + (size_t)h * 64;

  __shared__ __align__(16) __bf16 Vt[64 * ALDP];        // [d][key]
  __shared__ __align__(16) __bf16 Pl[4][16 * ALDP];     // per-wave P [q][key]

  // Q A-fragments (row m = l16, k-chunks quad*8, two 32-wide k-steps)
  bf16_8 qf[2];
  {
    const int qrow = q0 + wave * 16 + l16;
#pragma unroll
    for (int s = 0; s < 2; ++s)
      qf[s] = *(const bf16_8*)(qb + base + (size_t)qrow * E + s * 32 + quad * 8);
  }

  f32x4 o[4] = {};               // C-layout: col d = nt*16+l16, row q = quad*4+r
  float mrow[4], lrow[4];
#pragma unroll
  for (int r = 0; r < 4; ++r) { mrow[r] = -1e30f; lrow[r] = 0.f; }

  for (int kt = 0; kt <= qblk; ++kt) {
    const int k0 = kt * 64;
    __syncthreads();  // protect Vt readers of previous tile
    // stage V transposed: Vt[d][key]
#pragma unroll
    for (int u = 0; u < 2; ++u) {
      int i = tid + u * 256;            // 0..511
      int kr = i & 63, dq = i >> 6;     // key row 0..63, d-chunk 0..7
      bf16_8 vv = *(const bf16_8*)(vb + base + (size_t)(k0 + kr) * E + dq * 8);
#pragma unroll
      for (int j = 0; j < 8; ++j)
        Vt[(dq * 8 + j) * ALDP + kr] = vv[j];
    }
    __syncthreads();

    // S = Q @ K^T : 4 key col-tiles; B-frag = K rows read directly from global
    f32x4 sc[4] = {};
#pragma unroll
    for (int jj = 0; jj < 4; ++jj) {
#pragma unroll
      for (int s = 0; s < 2; ++s) {
        bf16_8 kf = *(const bf16_8*)(kb + base +
            (size_t)(k0 + jj * 16 + l16) * E + s * 32 + quad * 8);
        sc[jj] = __builtin_amdgcn_mfma_f32_16x16x32_bf16(qf[s], kf, sc[jj], 0, 0, 0);
      }
    }

    // online softmax (per C-layout row quad*4+r; stats reduced over 16-lane col group)
#pragma unroll
    for (int r = 0; r < 4; ++r) {
      float mx = -1e30f;
#pragma unroll
      for (int jj = 0; jj < 4; ++jj) {
        float v = sc[jj][r] * 0.125f;  // 1/sqrt(64)
        if (kt == qblk) {
          int key = k0 + jj * 16 + l16;
          int qq = q0 + wave * 16 + quad * 4 + r;
          if (key > qq) v = -1e30f;
        }
        sc[jj][r] = v;
        mx = fmaxf(mx, v);
      }
#pragma unroll
      for (int off = 1; off < 16; off <<= 1) mx = fmaxf(mx, __shfl_xor(mx, off));
      const float mn = fmaxf(mrow[r], mx);
      const float corr = __expf(mrow[r] - mn);
      float sum = 0.f;
#pragma unroll
      for (int jj = 0; jj < 4; ++jj) {
        float p = __expf(sc[jj][r] - mn);
        sc[jj][r] = p;
        sum += p;
      }
#pragma unroll
      for (int off = 1; off < 16; off <<= 1) sum += __shfl_xor(sum, off);
      lrow[r] = lrow[r] * corr + sum;
      mrow[r] = mn;
#pragma unroll
      for (int nt = 0; nt < 4; ++nt) o[nt][r] *= corr;
    }

    // P: C-layout regs -> wave-private LDS (no barrier needed; same-wave RAW
    // through LDS is a compiler-visible dependence -> lgkmcnt wait)
    __bf16* pw = &Pl[wave][0];
#pragma unroll
    for (int r = 0; r < 4; ++r)
#pragma unroll
      for (int jj = 0; jj < 4; ++jj)
        pw[(quad * 4 + r) * ALDP + jj * 16 + l16] = (__bf16)sc[jj][r];

    // O += P @ V : A-frag from Pl, B-frag from Vt
#pragma unroll
    for (int s = 0; s < 2; ++s) {
      bf16_8 pf = *(const bf16_8*)(&pw[l16 * ALDP + s * 32 + quad * 8]);
#pragma unroll
      for (int nt = 0; nt < 4; ++nt) {
        bf16_8 vf = *(const bf16_8*)(&Vt[(nt * 16 + l16) * ALDP + s * 32 + quad * 8]);
        o[nt] = __builtin_amdgcn_mfma_f32_16x16x32_bf16(pf, vf, o[nt], 0, 0, 0);
      }
    }
  }

  // epilogue: normalize, write bf16
#pragma unroll
  for (int r = 0; r < 4; ++r) {
    const float inv = 1.f / lrow[r];
    const int qq = q0 + wave * 16 + quad * 4 + r;
#pragma unroll
    for (int nt = 0; nt < 4; ++nt)
      ob[base + (size_t)qq * E + nt * 16 + l16] = __hip_bfloat16(o[nt][r] * inv);
  }
}

// ---------------------------------------------------------------- launch
extern "C" void kernel_launch(void* const* d_in, const int* in_sizes, int n_in,
                              void* d_out, int out_size, void* d_ws, size_t ws_size,
                              hipStream_t stream) {
  const int Bv = 2, S = 2048, E = 768, FF = 3072;
  const int M = Bv * S;  // 4096

  const float* x = (const float*)d_in[0];
  const float* wq = (const float*)d_in[1];
  const float* wk = (const float*)d_in[2];
  const float* wv = (const float*)d_in[3];
  const float* wo = (const float*)d_in[4];
  const float* bo = (const float*)d_in[5];
  const float* w1 = (const float*)d_in[6];
  const float* b1 = (const float*)d_in[7];
  const float* w2 = (const float*)d_in[8];
  const float* b2 = (const float*)d_in[9];
  const float* gamma = (const float*)d_in[10];
  const float* beta = (const float*)d_in[11];

  // ws: 5 slots of M*E bf16 = 31.5 MB.
  //   s0: xn -> attn -> y    s1..s3: q,k,v    hbuf = s1..s4 (M*FF bf16)
  //   res (fp32) lives in d_out and is finalized in place.
  __hip_bfloat16* slot = (__hip_bfloat16*)d_ws;
  const size_t ME = (size_t)M * E;
  __hip_bfloat16* xn = slot;           // s0
  __hip_bfloat16* attn = slot;         // s0 reuse (xn dead)
  __hip_bfloat16* y = slot;            // s0 reuse (attn dead)
  __hip_bfloat16* q = slot + ME;       // s1
  __hip_bfloat16* k = slot + 2 * ME;   // s2
  __hip_bfloat16* v = slot + 3 * ME;   // s3
  __hip_bfloat16* hbuf = slot + ME;    // s1..s4 (q,k,v dead by then)
  float* res = (float*)d_out;          // fp32 residual, finalized in place

  // 1. LN1 (x fp32 -> xn bf16)
  ln_kernel<<<M, 256, 0, stream>>>(x, gamma, beta, xn, E);
  // 2. Q/K/V projections
  dim3 gE(E / 128, M / 128);
  gemm_bt<0><<<gE, 256, 0, stream>>>(xn, wq, nullptr, nullptr, q, M, E, E);
  gemm_bt<0><<<gE, 256, 0, stream>>>(xn, wk, nullptr, nullptr, k, M, E, E);
  gemm_bt<0><<<gE, 256, 0, stream>>>(xn, wv, nullptr, nullptr, v, M, E, E);
  // 3. causal attention (q,k,v -> attn in s0)
  attn_mfma<<<dim3(24, 32), 256, 0, stream>>>(q, k, v, attn);
  // 4. output projection + bias + residual(x fp32) -> res (fp32, in d_out)
  gemm_bt<1><<<gE, 256, 0, stream>>>(attn, wo, bo, x, res, M, E, E);
  // 5. LN2 (res fp32 -> y bf16 in s0)
  ln_kernel<<<M, 256, 0, stream>>>(res, gamma, beta, y, E);
  // 6. FFN up + GELU(erf) -> hbuf bf16 (s1..s4)
  dim3 gF(FF / 128, M / 128);
  gemm_bt<2><<<gF, 256, 0, stream>>>(y, w1, b1, nullptr, hbuf, M, FF, E);
  // 7. FFN down + bias, accumulated into res in place -> d_out (fp32)
  gemm_bt<3><<<gE, 256, 0, stream>>>(hbuf, w2, b2, nullptr, d_out, M, E, FF);
}

// Round 9
// 398.230 us; speedup vs baseline: 4.2810x; 1.2035x over previous
//
#include <hip/hip_runtime.h>
#include <hip/hip_bf16.h>
#include <math.h>

typedef __bf16 bf16_8 __attribute__((ext_vector_type(8)));
typedef float f32x4 __attribute__((ext_vector_type(4)));

// ---------------------------------------------------------------- LayerNorm (fp32 in -> bf16 out)
__global__ __launch_bounds__(256) void ln_kernel(
    const float* __restrict__ x, const float* __restrict__ g,
    const float* __restrict__ b, __hip_bfloat16* __restrict__ out, int cols) {
  const int row = blockIdx.x;
  const int t = threadIdx.x;
  float loc[3];
  float s = 0.f, s2 = 0.f;
#pragma unroll
  for (int i = 0; i < 3; ++i) {
    float v = x[(size_t)row * cols + t + i * 256];
    loc[i] = v;
    s += v;
    s2 += v * v;
  }
#pragma unroll
  for (int off = 32; off; off >>= 1) {
    s += __shfl_down(s, off);
    s2 += __shfl_down(s2, off);
  }
  __shared__ float red[2][4];
  const int lane = t & 63, w = t >> 6;
  if (lane == 0) {
    red[0][w] = s;
    red[1][w] = s2;
  }
  __syncthreads();
  s = red[0][0] + red[0][1] + red[0][2] + red[0][3];
  s2 = red[1][0] + red[1][1] + red[1][2] + red[1][3];
  const float mu = s / cols;
  const float var = s2 / cols - mu * mu;
  const float rs = rsqrtf(var + 1e-5f);
  __hip_bfloat16* orow = out + (size_t)row * cols;
#pragma unroll
  for (int i = 0; i < 3; ++i) {
    int c = t + i * 256;
    orow[c] = __hip_bfloat16((loc[i] - mu) * rs * g[c] + b[c]);
  }
}

// ---------------------------------------------------------------- GEMM (A[M,K] bf16 ws @ B[N,K]^T fp32 input)
// MODE 0 (QKV):  N=2304 over {wq,wk,wv}; out bf16 into contiguous q,k,v slots
// MODE 1 (GELU): out bf16 = gelu_erf(acc + bias)
// MODE 2 (ACC):  split-K over gridDim.z; atomicAdd fp32 into out; bias at kz==0
template <int MODE>
__global__ __launch_bounds__(256) void gemm_bt(
    const __hip_bfloat16* __restrict__ A, const float* __restrict__ B0,
    const float* __restrict__ B1, const float* __restrict__ B2,
    const float* __restrict__ bias, void* __restrict__ out,
    int M, int N, int K) {
  constexpr int BM = 128, BN = 128, BK = 32, LDP = 40;
  __shared__ __align__(16) __bf16 As[BM * LDP];
  __shared__ __align__(16) __bf16 Bs[BN * LDP];
  const int tid = threadIdx.x;
  const int m0 = blockIdx.y * BM;
  const int n0 = blockIdx.x * BN;
  const int wave = tid >> 6;
  const int lane = tid & 63;
  const int quad = lane >> 4;
  const int l16 = lane & 15;
  const int wm = (wave & 1) * 64;
  const int wn = (wave >> 1) * 64;

  int tsel = 0, nloc = n0;
  const float* Bw = B0;
  if constexpr (MODE == 0) {
    tsel = n0 / 768;
    nloc = n0 - tsel * 768;
    Bw = (tsel == 0) ? B0 : (tsel == 1) ? B1 : B2;
  }
  int kbase = 0, kcnt = K;
  if constexpr (MODE == 2) {
    kcnt = K / gridDim.z;
    kbase = blockIdx.z * kcnt;
  }

  f32x4 acc[4][4] = {};

  for (int k0 = kbase; k0 < kbase + kcnt; k0 += BK) {
    __syncthreads();
#pragma unroll
    for (int u = 0; u < 2; ++u) {
      int i = tid + u * 256;          // 0..511
      int row = i >> 2, kq = i & 3;   // row 0..127, 8-elem chunk 0..3
      *(bf16_8*)(&As[row * LDP + kq * 8]) =
          *(const bf16_8*)(A + (size_t)(m0 + row) * K + k0 + kq * 8);
      const float* src = Bw + (size_t)(nloc + row) * K + k0 + kq * 8;
      float4 f0 = *(const float4*)src;
      float4 f1 = *(const float4*)(src + 4);
      bf16_8 bv;
      bv[0] = (__bf16)f0.x; bv[1] = (__bf16)f0.y; bv[2] = (__bf16)f0.z; bv[3] = (__bf16)f0.w;
      bv[4] = (__bf16)f1.x; bv[5] = (__bf16)f1.y; bv[6] = (__bf16)f1.z; bv[7] = (__bf16)f1.w;
      *(bf16_8*)(&Bs[row * LDP + kq * 8]) = bv;
    }
    __syncthreads();
    bf16_8 af[4], bfr[4];
#pragma unroll
    for (int i = 0; i < 4; ++i)
      af[i] = *(const bf16_8*)(&As[(wm + i * 16 + l16) * LDP + quad * 8]);
#pragma unroll
    for (int j = 0; j < 4; ++j)
      bfr[j] = *(const bf16_8*)(&Bs[(wn + j * 16 + l16) * LDP + quad * 8]);
#pragma unroll
    for (int i = 0; i < 4; ++i)
#pragma unroll
      for (int j = 0; j < 4; ++j)
        acc[i][j] =
            __builtin_amdgcn_mfma_f32_16x16x32_bf16(af[i], bfr[j], acc[i][j], 0, 0, 0);
  }

#pragma unroll
  for (int i = 0; i < 4; ++i) {
#pragma unroll
    for (int j = 0; j < 4; ++j) {
#pragma unroll
      for (int r = 0; r < 4; ++r) {
        const int row = m0 + wm + i * 16 + quad * 4 + r;
        const int coll = nloc + wn + j * 16 + l16;  // col within the tensor
        const float v = acc[i][j][r];
        if constexpr (MODE == 0) {
          const size_t idx = (size_t)tsel * M * 768 + (size_t)row * 768 + coll;
          ((__hip_bfloat16*)out)[idx] = __hip_bfloat16(v);
        } else if constexpr (MODE == 1) {
          const size_t idx = (size_t)row * N + coll;
          float tt = v + bias[coll];
          float gl = 0.5f * tt * (1.0f + erff(tt * 0.70710678118654752f));
          ((__hip_bfloat16*)out)[idx] = __hip_bfloat16(gl);
        } else {
          const size_t idx = (size_t)row * N + coll;
          float add = v + (blockIdx.z == 0 ? bias[coll] : 0.f);
          atomicAdd((float*)out + idx, add);
        }
      }
    }
  }
}

// ---------------------------------------------------------------- MFMA flash attention
// Grid: (24 bh, 32 q-tiles). Block: 256 thr = 4 waves; wave owns 16 queries.
#define ALDP 72
__global__ __launch_bounds__(256) void attn_mfma(
    const __hip_bfloat16* __restrict__ qb, const __hip_bfloat16* __restrict__ kb,
    const __hip_bfloat16* __restrict__ vb, __hip_bfloat16* __restrict__ ob) {
  const int S = 2048, H = 12, E = 768;
  const int bh = blockIdx.x;          // 0..23
  const int b = bh / H, h = bh % H;
  const int qblk = 31 - blockIdx.y;   // heaviest q-tiles dispatch first
  const int q0 = qblk * 64;
  const int tid = threadIdx.x;
  const int wave = tid >> 6;
  const int lane = tid & 63;
  const int quad = lane >> 4;
  const int l16 = lane & 15;
  const size_t base = (size_t)b * S * E + (size_t)h * 64;

  __shared__ __align__(16) __bf16 Vt[64 * ALDP];        // [d][key]
  __shared__ __align__(16) __bf16 Pl[4][16 * ALDP];     // per-wave P [q][key]

  bf16_8 qf[2];
  {
    const int qrow = q0 + wave * 16 + l16;
#pragma unroll
    for (int s = 0; s < 2; ++s)
      qf[s] = *(const bf16_8*)(qb + base + (size_t)qrow * E + s * 32 + quad * 8);
  }

  f32x4 o[4] = {};
  float mrow[4], lrow[4];
#pragma unroll
  for (int r = 0; r < 4; ++r) { mrow[r] = -1e30f; lrow[r] = 0.f; }

  for (int kt = 0; kt <= qblk; ++kt) {
    const int k0 = kt * 64;
    __syncthreads();
#pragma unroll
    for (int u = 0; u < 2; ++u) {
      int i = tid + u * 256;
      int kr = i & 63, dq = i >> 6;
      bf16_8 vv = *(const bf16_8*)(vb + base + (size_t)(k0 + kr) * E + dq * 8);
#pragma unroll
      for (int j = 0; j < 8; ++j)
        Vt[(dq * 8 + j) * ALDP + kr] = vv[j];
    }
    __syncthreads();

    f32x4 sc[4] = {};
#pragma unroll
    for (int jj = 0; jj < 4; ++jj) {
#pragma unroll
      for (int s = 0; s < 2; ++s) {
        bf16_8 kf = *(const bf16_8*)(kb + base +
            (size_t)(k0 + jj * 16 + l16) * E + s * 32 + quad * 8);
        sc[jj] = __builtin_amdgcn_mfma_f32_16x16x32_bf16(qf[s], kf, sc[jj], 0, 0, 0);
      }
    }

#pragma unroll
    for (int r = 0; r < 4; ++r) {
      float mx = -1e30f;
#pragma unroll
      for (int jj = 0; jj < 4; ++jj) {
        float v = sc[jj][r] * 0.125f;
        if (kt == qblk) {
          int key = k0 + jj * 16 + l16;
          int qq = q0 + wave * 16 + quad * 4 + r;
          if (key > qq) v = -1e30f;
        }
        sc[jj][r] = v;
        mx = fmaxf(mx, v);
      }
#pragma unroll
      for (int off = 1; off < 16; off <<= 1) mx = fmaxf(mx, __shfl_xor(mx, off));
      const float mn = fmaxf(mrow[r], mx);
      const float corr = __expf(mrow[r] - mn);
      float sum = 0.f;
#pragma unroll
      for (int jj = 0; jj < 4; ++jj) {
        float p = __expf(sc[jj][r] - mn);
        sc[jj][r] = p;
        sum += p;
      }
#pragma unroll
      for (int off = 1; off < 16; off <<= 1) sum += __shfl_xor(sum, off);
      lrow[r] = lrow[r] * corr + sum;
      mrow[r] = mn;
#pragma unroll
      for (int nt = 0; nt < 4; ++nt) o[nt][r] *= corr;
    }

    __bf16* pw = &Pl[wave][0];
#pragma unroll
    for (int r = 0; r < 4; ++r)
#pragma unroll
      for (int jj = 0; jj < 4; ++jj)
        pw[(quad * 4 + r) * ALDP + jj * 16 + l16] = (__bf16)sc[jj][r];

#pragma unroll
    for (int s = 0; s < 2; ++s) {
      bf16_8 pf = *(const bf16_8*)(&pw[l16 * ALDP + s * 32 + quad * 8]);
#pragma unroll
      for (int nt = 0; nt < 4; ++nt) {
        bf16_8 vf = *(const bf16_8*)(&Vt[(nt * 16 + l16) * ALDP + s * 32 + quad * 8]);
        o[nt] = __builtin_amdgcn_mfma_f32_16x16x32_bf16(pf, vf, o[nt], 0, 0, 0);
      }
    }
  }

#pragma unroll
  for (int r = 0; r < 4; ++r) {
    const float inv = 1.f / lrow[r];
    const int qq = q0 + wave * 16 + quad * 4 + r;
#pragma unroll
    for (int nt = 0; nt < 4; ++nt)
      ob[base + (size_t)qq * E + nt * 16 + l16] = __hip_bfloat16(o[nt][r] * inv);
  }
}

// ---------------------------------------------------------------- launch
extern "C" void kernel_launch(void* const* d_in, const int* in_sizes, int n_in,
                              void* d_out, int out_size, void* d_ws, size_t ws_size,
                              hipStream_t stream) {
  const int Bv = 2, S = 2048, E = 768, FF = 3072;
  const int M = Bv * S;  // 4096

  const float* x = (const float*)d_in[0];
  const float* wq = (const float*)d_in[1];
  const float* wk = (const float*)d_in[2];
  const float* wv = (const float*)d_in[3];
  const float* wo = (const float*)d_in[4];
  const float* bo = (const float*)d_in[5];
  const float* w1 = (const float*)d_in[6];
  const float* b1 = (const float*)d_in[7];
  const float* w2 = (const float*)d_in[8];
  const float* b2 = (const float*)d_in[9];
  const float* gamma = (const float*)d_in[10];
  const float* beta = (const float*)d_in[11];

  // ws: 5 slots of M*E bf16 = 31.5 MB.
  //   s0: xn -> attn -> y    s1..s3: q,k,v (contiguous for fused QKV)
  //   hbuf = s1..s4    res (fp32) lives in d_out, seeded by async copy of x.
  __hip_bfloat16* slot = (__hip_bfloat16*)d_ws;
  const size_t ME = (size_t)M * E;
  __hip_bfloat16* xn = slot;           // s0
  __hip_bfloat16* attn = slot;         // s0 reuse (xn dead)
  __hip_bfloat16* y = slot;            // s0 reuse (attn dead)
  __hip_bfloat16* q = slot + ME;       // s1 (k=s2, v=s3 contiguous)
  __hip_bfloat16* k = slot + 2 * ME;   // s2
  __hip_bfloat16* v = slot + 3 * ME;   // s3
  __hip_bfloat16* hbuf = slot + ME;    // s1..s4 (q,k,v dead by then)
  float* res = (float*)d_out;          // fp32 residual, accumulated in place

  // 1. LN1 (x fp32 -> xn bf16)
  ln_kernel<<<M, 256, 0, stream>>>(x, gamma, beta, xn, E);
  // 2. fused Q/K/V projection: N = 2304 across {wq,wk,wv} -> q,k,v slots
  gemm_bt<0><<<dim3(18, 32), 256, 0, stream>>>(xn, wq, wk, wv, nullptr, q, M, 2304, E);
  // 3. causal flash attention (q,k,v -> attn in s0)
  attn_mfma<<<dim3(24, 32), 256, 0, stream>>>(q, k, v, attn);
  // 4a. seed residual: res = x (fp32 d2d copy, graph-safe)
  hipMemcpyAsync(d_out, x, ME * sizeof(float), hipMemcpyDeviceToDevice, stream);
  // 4b. attn-proj accumulate: res += attn@wo^T + bo   (split-K 2 -> 384 blocks)
  gemm_bt<2><<<dim3(6, 32, 2), 256, 0, stream>>>(attn, wo, nullptr, nullptr, bo, res, M, E, E);
  // 5. LN2 (res fp32 -> y bf16 in s0)
  ln_kernel<<<M, 256, 0, stream>>>(res, gamma, beta, y, E);
  // 6. FFN up + GELU(erf) -> hbuf bf16 (768 blocks)
  gemm_bt<1><<<dim3(24, 32), 256, 0, stream>>>(y, w1, nullptr, nullptr, b1, hbuf, M, FF, E);
  // 7. FFN down accumulate: res += hbuf@w2^T + b2   (split-K 4 -> 768 blocks)
  gemm_bt<2><<<dim3(6, 32, 4), 256, 0, stream>>>(hbuf, w2, nullptr, nullptr, b2, d_out, M, E, FF);
}

// Round 10
// 356.629 us; speedup vs baseline: 4.7804x; 1.1167x over previous
//
#include <hip/hip_runtime.h>
#include <hip/hip_bf16.h>
#include <math.h>

typedef __bf16 bf16_8 __attribute__((ext_vector_type(8)));
typedef float f32x4 __attribute__((ext_vector_type(4)));

// ---------------------------------------------------------------- LayerNorm (fp32 in -> bf16 out)
__global__ __launch_bounds__(256) void ln_kernel(
    const float* __restrict__ x, const float* __restrict__ g,
    const float* __restrict__ b, __hip_bfloat16* __restrict__ out, int cols) {
  const int row = blockIdx.x;
  const int t = threadIdx.x;
  float loc[3];
  float s = 0.f, s2 = 0.f;
#pragma unroll
  for (int i = 0; i < 3; ++i) {
    float v = x[(size_t)row * cols + t + i * 256];
    loc[i] = v;
    s += v;
    s2 += v * v;
  }
#pragma unroll
  for (int off = 32; off; off >>= 1) {
    s += __shfl_down(s, off);
    s2 += __shfl_down(s2, off);
  }
  __shared__ float red[2][4];
  const int lane = t & 63, w = t >> 6;
  if (lane == 0) {
    red[0][w] = s;
    red[1][w] = s2;
  }
  __syncthreads();
  s = red[0][0] + red[0][1] + red[0][2] + red[0][3];
  s2 = red[1][0] + red[1][1] + red[1][2] + red[1][3];
  const float mu = s / cols;
  const float var = s2 / cols - mu * mu;
  const float rs = rsqrtf(var + 1e-5f);
  __hip_bfloat16* orow = out + (size_t)row * cols;
#pragma unroll
  for (int i = 0; i < 3; ++i) {
    int c = t + i * 256;
    orow[c] = __hip_bfloat16((loc[i] - mu) * rs * g[c] + b[c]);
  }
}

// ---------------------------------------------------------------- GEMM (A[M,K] bf16 ws @ B[N,K]^T fp32 input)
// MODE 0 (QKV):  N=2304 over {wq,wk,wv}; out bf16 into contiguous q,k,v slots
// MODE 1 (GELU): out bf16 = gelu_erf(acc + bias)
// MODE 2 (ACC):  split-K over gridDim.z; atomicAdd fp32 into out; bias at kz==0
template <int MODE>
__global__ __launch_bounds__(256) void gemm_bt(
    const __hip_bfloat16* __restrict__ A, const float* __restrict__ B0,
    const float* __restrict__ B1, const float* __restrict__ B2,
    const float* __restrict__ bias, void* __restrict__ out,
    int M, int N, int K) {
  constexpr int BM = 128, BN = 128, BK = 32, LDP = 40;
  __shared__ __align__(16) __bf16 As[BM * LDP];
  __shared__ __align__(16) __bf16 Bs[BN * LDP];
  const int tid = threadIdx.x;
  const int m0 = blockIdx.y * BM;
  const int n0 = blockIdx.x * BN;
  const int wave = tid >> 6;
  const int lane = tid & 63;
  const int quad = lane >> 4;
  const int l16 = lane & 15;
  const int wm = (wave & 1) * 64;
  const int wn = (wave >> 1) * 64;

  int tsel = 0, nloc = n0;
  const float* Bw = B0;
  if constexpr (MODE == 0) {
    tsel = n0 / 768;
    nloc = n0 - tsel * 768;
    Bw = (tsel == 0) ? B0 : (tsel == 1) ? B1 : B2;
  }
  int kbase = 0, kcnt = K;
  if constexpr (MODE == 2) {
    kcnt = K / gridDim.z;
    kbase = blockIdx.z * kcnt;
  }

  f32x4 acc[4][4] = {};

  for (int k0 = kbase; k0 < kbase + kcnt; k0 += BK) {
    __syncthreads();
#pragma unroll
    for (int u = 0; u < 2; ++u) {
      int i = tid + u * 256;          // 0..511
      int row = i >> 2, kq = i & 3;   // row 0..127, 8-elem chunk 0..3
      *(bf16_8*)(&As[row * LDP + kq * 8]) =
          *(const bf16_8*)(A + (size_t)(m0 + row) * K + k0 + kq * 8);
      const float* src = Bw + (size_t)(nloc + row) * K + k0 + kq * 8;
      float4 f0 = *(const float4*)src;
      float4 f1 = *(const float4*)(src + 4);
      bf16_8 bv;
      bv[0] = (__bf16)f0.x; bv[1] = (__bf16)f0.y; bv[2] = (__bf16)f0.z; bv[3] = (__bf16)f0.w;
      bv[4] = (__bf16)f1.x; bv[5] = (__bf16)f1.y; bv[6] = (__bf16)f1.z; bv[7] = (__bf16)f1.w;
      *(bf16_8*)(&Bs[row * LDP + kq * 8]) = bv;
    }
    __syncthreads();
    bf16_8 af[4], bfr[4];
#pragma unroll
    for (int i = 0; i < 4; ++i)
      af[i] = *(const bf16_8*)(&As[(wm + i * 16 + l16) * LDP + quad * 8]);
#pragma unroll
    for (int j = 0; j < 4; ++j)
      bfr[j] = *(const bf16_8*)(&Bs[(wn + j * 16 + l16) * LDP + quad * 8]);
#pragma unroll
    for (int i = 0; i < 4; ++i)
#pragma unroll
      for (int j = 0; j < 4; ++j)
        acc[i][j] =
            __builtin_amdgcn_mfma_f32_16x16x32_bf16(af[i], bfr[j], acc[i][j], 0, 0, 0);
  }

#pragma unroll
  for (int i = 0; i < 4; ++i) {
#pragma unroll
    for (int j = 0; j < 4; ++j) {
#pragma unroll
      for (int r = 0; r < 4; ++r) {
        const int row = m0 + wm + i * 16 + quad * 4 + r;
        const int coll = nloc + wn + j * 16 + l16;
        const float v = acc[i][j][r];
        if constexpr (MODE == 0) {
          const size_t idx = (size_t)tsel * M * 768 + (size_t)row * 768 + coll;
          ((__hip_bfloat16*)out)[idx] = __hip_bfloat16(v);
        } else if constexpr (MODE == 1) {
          const size_t idx = (size_t)row * N + coll;
          float tt = v + bias[coll];
          float gl = 0.5f * tt * (1.0f + erff(tt * 0.70710678118654752f));
          ((__hip_bfloat16*)out)[idx] = __hip_bfloat16(gl);
        } else {
          const size_t idx = (size_t)row * N + coll;
          float add = v + (blockIdx.z == 0 ? bias[coll] : 0.f);
          atomicAdd((float*)out + idx, add);
        }
      }
    }
  }
}

// ---------------------------------------------------------------- work counter
__global__ void zero_ctr(int* __restrict__ c) {
  if (threadIdx.x == 0) *c = 0;
}

// ---------------------------------------------------------------- MFMA flash attention (S^T / O^T form)
// Persistent blocks + atomic work-stealing over heavy-first (qblk desc) tasks.
// Per 64-key tile: S^T = K·Q^T (A=K m=key, B=Q n=query) -> per-lane softmax
// (stats indexed by q=l16; only 4 shfls/tile) -> P^T to wave-private LDS ->
// O^T += mfma(V^T-frag, P-frag). Epilogue: O^T -> LDS -> coalesced store.
#define ALDP 72
__global__ __launch_bounds__(256) void attn_mfma(
    const __hip_bfloat16* __restrict__ qb, const __hip_bfloat16* __restrict__ kb,
    const __hip_bfloat16* __restrict__ vb, __hip_bfloat16* __restrict__ ob,
    int* __restrict__ ctr) {
  const int S = 2048, H = 12, E = 768;
  const int tid = threadIdx.x;
  const int wave = tid >> 6;
  const int lane = tid & 63;
  const int quad = lane >> 4;
  const int l16 = lane & 15;

  __shared__ __align__(16) __bf16 Ks[64 * ALDP];     // [key][d]
  __shared__ __align__(16) __bf16 Vt[64 * ALDP];     // [d][key]
  __shared__ __align__(16) __bf16 Pl[4][16 * ALDP];  // wave-private [q][*]
  __shared__ int task;

  for (;;) {
    if (tid == 0) task = atomicAdd(ctr, 1);
    __syncthreads();
    const int t = task;
    if (t >= 24 * 32) return;
    const int qblk = 31 - (t / 24);            // heaviest first
    const int bh = t - (t / 24) * 24;
    const int b = bh / H, h = bh - b * H;
    const int q0 = qblk * 64;
    const int qw = q0 + wave * 16;             // wave's first query
    const size_t base = (size_t)b * S * E + (size_t)h * 64;

    // Q fragments (B-operand: n = q = l16, k = d)
    bf16_8 qf[2];
#pragma unroll
    for (int s = 0; s < 2; ++s)
      qf[s] = *(const bf16_8*)(qb + base + (size_t)(qw + l16) * E + s * 32 + quad * 8);

    f32x4 o[4] = {};              // O^T: row d = dt*16+quad*4+r, col q = l16
    float mq = -1e30f, lq = 0.f;  // per-lane stats for query l16

    for (int kt = 0; kt <= qblk; ++kt) {
      const int k0 = kt * 64;
      __syncthreads();
      // stage K (vector b128) and V transposed (scalar)
#pragma unroll
      for (int u = 0; u < 2; ++u) {
        int i = tid + u * 256;
        int kr = i >> 3, kc = i & 7;
        *(bf16_8*)(&Ks[kr * ALDP + kc * 8]) =
            *(const bf16_8*)(kb + base + (size_t)(k0 + kr) * E + kc * 8);
      }
#pragma unroll
      for (int u = 0; u < 2; ++u) {
        int i = tid + u * 256;
        int kr = i & 63, dq = i >> 6;
        bf16_8 vv = *(const bf16_8*)(vb + base + (size_t)(k0 + kr) * E + dq * 8);
#pragma unroll
        for (int j = 0; j < 8; ++j) Vt[(dq * 8 + j) * ALDP + kr] = vv[j];
      }
      __syncthreads();

      // S^T = K·Q^T
      f32x4 sc[4] = {};
#pragma unroll
      for (int jj = 0; jj < 4; ++jj)
#pragma unroll
        for (int s = 0; s < 2; ++s) {
          bf16_8 kf = *(const bf16_8*)(&Ks[(jj * 16 + l16) * ALDP + s * 32 + quad * 8]);
          sc[jj] = __builtin_amdgcn_mfma_f32_16x16x32_bf16(kf, qf[s], sc[jj], 0, 0, 0);
        }

      // scale + causal mask + per-lane max over the 16 (jj,r) key-scores
      float mx = -1e30f;
#pragma unroll
      for (int jj = 0; jj < 4; ++jj)
#pragma unroll
        for (int r = 0; r < 4; ++r) {
          float v = sc[jj][r] * 0.125f;  // 1/sqrt(64)
          if (kt == qblk && (k0 + jj * 16 + quad * 4 + r) > (qw + l16)) v = -1e30f;
          sc[jj][r] = v;
          mx = fmaxf(mx, v);
        }
      mx = fmaxf(mx, __shfl_xor(mx, 16));
      mx = fmaxf(mx, __shfl_xor(mx, 32));
      const float mn = fmaxf(mq, mx);
      const float corr = __expf(mq - mn);
      mq = mn;
      float sum = 0.f;
#pragma unroll
      for (int jj = 0; jj < 4; ++jj)
#pragma unroll
        for (int r = 0; r < 4; ++r) {
          float p = __expf(sc[jj][r] - mn);
          sc[jj][r] = p;
          sum += p;
        }
      sum += __shfl_xor(sum, 16);
      sum += __shfl_xor(sum, 32);
      lq = lq * corr + sum;
      // O^T rescale: column q = l16 -> lane-local corr, no shuffle
#pragma unroll
      for (int nt = 0; nt < 4; ++nt)
#pragma unroll
        for (int r = 0; r < 4; ++r) o[nt][r] *= corr;

      // P^T -> wave-private LDS as [q][key] (same-wave RAW, lgkm-tracked)
      __bf16* pw = &Pl[wave][0];
#pragma unroll
      for (int jj = 0; jj < 4; ++jj)
#pragma unroll
        for (int r = 0; r < 4; ++r)
          pw[l16 * ALDP + jj * 16 + quad * 4 + r] = (__bf16)sc[jj][r];

      // O^T += V^T·P^T : A = V^T-frag (m=d), B = P-frag (n=q)
#pragma unroll
      for (int s = 0; s < 2; ++s) {
        bf16_8 pf = *(const bf16_8*)(&pw[l16 * ALDP + s * 32 + quad * 8]);
#pragma unroll
        for (int dt = 0; dt < 4; ++dt) {
          bf16_8 vf = *(const bf16_8*)(&Vt[(dt * 16 + l16) * ALDP + s * 32 + quad * 8]);
          o[dt] = __builtin_amdgcn_mfma_f32_16x16x32_bf16(vf, pf, o[dt], 0, 0, 0);
        }
      }
    }

    // epilogue: normalize (lane-local 1/lq), transpose via Pl, coalesced store
    const float inv = 1.f / lq;
    __bf16* pw = &Pl[wave][0];
#pragma unroll
    for (int dt = 0; dt < 4; ++dt)
#pragma unroll
      for (int r = 0; r < 4; ++r)
        pw[l16 * ALDP + dt * 16 + quad * 4 + r] = (__bf16)(o[dt][r] * inv);
#pragma unroll
    for (int u = 0; u < 2; ++u) {
      int j = lane + u * 64;          // 0..127
      int ql = j >> 3, ch = j & 7;    // query-local 0..15, 8-elem chunk 0..7
      bf16_8 ov = *(const bf16_8*)(&pw[ql * ALDP + ch * 8]);
      *(bf16_8*)(ob + base + (size_t)(qw + ql) * E + ch * 8) = ov;
    }
  }
}

// ---------------------------------------------------------------- launch
extern "C" void kernel_launch(void* const* d_in, const int* in_sizes, int n_in,
                              void* d_out, int out_size, void* d_ws, size_t ws_size,
                              hipStream_t stream) {
  const int Bv = 2, S = 2048, E = 768, FF = 3072;
  const int M = Bv * S;  // 4096

  const float* x = (const float*)d_in[0];
  const float* wq = (const float*)d_in[1];
  const float* wk = (const float*)d_in[2];
  const float* wv = (const float*)d_in[3];
  const float* wo = (const float*)d_in[4];
  const float* bo = (const float*)d_in[5];
  const float* w1 = (const float*)d_in[6];
  const float* b1 = (const float*)d_in[7];
  const float* w2 = (const float*)d_in[8];
  const float* b2 = (const float*)d_in[9];
  const float* gamma = (const float*)d_in[10];
  const float* beta = (const float*)d_in[11];

  // ws: [ctr + pad 256B][5 slots of M*E bf16] = 31.46 MB.
  //   s0: xn -> attn -> y    s1..s3: q,k,v (contiguous for fused QKV)
  //   hbuf = s1..s4    res (fp32) lives in d_out, seeded by async copy of x.
  int* ctr = (int*)d_ws;
  __hip_bfloat16* slot = (__hip_bfloat16*)((char*)d_ws + 256);
  const size_t ME = (size_t)M * E;
  __hip_bfloat16* xn = slot;           // s0
  __hip_bfloat16* attn = slot;         // s0 reuse (xn dead)
  __hip_bfloat16* y = slot;            // s0 reuse (attn dead)
  __hip_bfloat16* q = slot + ME;       // s1 (k=s2, v=s3 contiguous)
  __hip_bfloat16* k = slot + 2 * ME;   // s2
  __hip_bfloat16* v = slot + 3 * ME;   // s3
  __hip_bfloat16* hbuf = slot + ME;    // s1..s4 (q,k,v dead by then)
  float* res = (float*)d_out;          // fp32 residual, accumulated in place

  // 1. LN1 (x fp32 -> xn bf16)
  ln_kernel<<<M, 256, 0, stream>>>(x, gamma, beta, xn, E);
  // 2. fused Q/K/V projection: N = 2304 across {wq,wk,wv} -> q,k,v slots
  gemm_bt<0><<<dim3(18, 32), 256, 0, stream>>>(xn, wq, wk, wv, nullptr, q, M, 2304, E);
  // 3. causal flash attention (persistent, work-stealing)
  zero_ctr<<<1, 64, 0, stream>>>(ctr);
  attn_mfma<<<768, 256, 0, stream>>>(q, k, v, attn, ctr);
  // 4a. seed residual: res = x (fp32 d2d copy, graph-safe)
  hipMemcpyAsync(d_out, x, ME * sizeof(float), hipMemcpyDeviceToDevice, stream);
  // 4b. attn-proj accumulate: res += attn@wo^T + bo   (split-K 2 -> 384 blocks)
  gemm_bt<2><<<dim3(6, 32, 2), 256, 0, stream>>>(attn, wo, nullptr, nullptr, bo, res, M, E, E);
  // 5. LN2 (res fp32 -> y bf16 in s0)
  ln_kernel<<<M, 256, 0, stream>>>(res, gamma, beta, y, E);
  // 6. FFN up + GELU(erf) -> hbuf bf16 (768 blocks)
  gemm_bt<1><<<dim3(24, 32), 256, 0, stream>>>(y, w1, nullptr, nullptr, b1, hbuf, M, FF, E);
  // 7. FFN down accumulate: res += hbuf@w2^T + b2   (split-K 4 -> 768 blocks)
  gemm_bt<2><<<dim3(6, 32, 4), 256, 0, stream>>>(hbuf, w2, nullptr, nullptr, b2, d_out, M, E, FF);
}